// Round 6
// baseline (531.935 us; speedup 1.0000x reference)
//
#include <hip/hip_runtime.h>
#include <stdint.h>

typedef unsigned short u16;
typedef unsigned int u32;

#define NV 400000
#define KOFF 27
#define EPS_BN 1e-5f

#define INV_ELEMS (KOFF * NV)            // 10.8M
#define INV_BYTES (INV_ELEMS * 4)        // 43.2 MB
#define FEATSBF_OFF INV_BYTES            // bf16 feats: 51.2 MB
#define WT_OFF (FEATSBF_OFF + NV * 64 * 2)
#define STATS_OFF (WT_OFF + KOFF * 64 * 64 * 2)

#define CVT_BLOCKS 25000                 // NV*64/4/256
#define BUILD_BLOCKS 42188               // ceil(INV_ELEMS/256)
#define WT_BLOCKS 432                    // ceil(KOFF*4096/256)
#define PREP_BLOCKS (CVT_BLOCKS + BUILD_BLOCKS + WT_BLOCKS)

using short8 = __attribute__((ext_vector_type(8))) short;
using floatx16 = __attribute__((ext_vector_type(16))) float;

__device__ __forceinline__ u16 f2bf(float f) {
  u32 u = __float_as_uint(f);
  u += 0x7FFFu + ((u >> 16) & 1u);
  return (u16)(u >> 16);
}

// ---------------- fused prep: cvt feats -> bf16 | build inv map | transpose W ----------------
__global__ void k_prep(const float* __restrict__ feats, u16* __restrict__ featsBf,
                       const int* __restrict__ in_idx, const int* __restrict__ out_idx,
                       const float* __restrict__ mask, int* __restrict__ inv,
                       const float* __restrict__ W, u16* __restrict__ Wt) {
  const int b = blockIdx.x;
  const int tid = threadIdx.x;
  if (b < CVT_BLOCKS) {
    // feats fp32 -> bf16, one float4 per thread
    int i = b * 256 + tid;
    float4 v = ((const float4*)feats)[i];
    ushort4 o;
    o.x = f2bf(v.x); o.y = f2bf(v.y); o.z = f2bf(v.z); o.w = f2bf(v.w);
    ((ushort4*)featsBf)[i] = o;
  } else if (b < CVT_BLOCKS + BUILD_BLOCKS) {
    // inverse map: inv[k][out_idx] = in_idx (valid out_idx distinct within k)
    int t = (b - CVT_BLOCKS) * 256 + tid;
    if (t < INV_ELEMS && mask[t] != 0.0f) {
      int k = t / NV;
      inv[k * NV + out_idx[t]] = in_idx[t];
    }
  } else {
    // Wt[k][o][c] = bf16(W[k][c][o])
    int t = (b - CVT_BLOCKS - BUILD_BLOCKS) * 256 + tid;
    if (t < KOFF * 64 * 64) {
      int k = t >> 12, rem = t & 4095, c = rem >> 6, o = rem & 63;
      Wt[(k << 12) + (o << 6) + c] = f2bf(W[t]);
    }
  }
}

// ---------------- main: barrier-free k-loop, direct-global B, 32x32x16 MFMA ----------------
// Block = 256 output rows, 4 waves, each wave owns a 64x64 tile (2x2 of 32x32).
// W tiles (216 KB total, read by all 1563 blocks) are L1/L2-resident: B fragments are
// loaded straight from global -> no LDS staging, NO barriers in the k-loop.
// A gather keeps the 1-ahead parity prefetch (srcs 2 ahead). 3 waves/SIMD via launch_bounds.
__global__ void __launch_bounds__(256, 3)
k_main(const u16* __restrict__ feats, const int* __restrict__ inv,
       const u16* __restrict__ Wt, float* __restrict__ out, float* __restrict__ stats) {
  __shared__ float redS[4][64];
  __shared__ float redQ[4][64];

  const int t = threadIdx.x;
  const int lane = t & 63;
  const int wave = t >> 6;
  const int lo = lane & 31;        // A row within 32-row group / D col within 32-col group
  const int hi = lane >> 5;        // k-half selector of the fragment
  const int rbase = blockIdx.x * 256 + wave * 64;
  const int row0 = rbase + lo;
  const int row1 = rbase + 32 + lo;
  const bool v0 = row0 < NV;
  const bool v1 = row1 < NV;

  const floatx16 z16 = {0.f, 0.f, 0.f, 0.f, 0.f, 0.f, 0.f, 0.f,
                        0.f, 0.f, 0.f, 0.f, 0.f, 0.f, 0.f, 0.f};
  floatx16 acc00 = z16, acc01 = z16, acc10 = z16, acc11 = z16;

  // per-lane base into W^T tile: row lo, k-slice hi  (row 32+lo is +2048)
  const u16* wbase = Wt + lo * 64 + hi * 8;

#define GATHER(A0, A1, s0, s1)                                        \
  {                                                                   \
    const short8 z8 = {0, 0, 0, 0, 0, 0, 0, 0};                       \
    A0[0] = z8; A0[1] = z8; A0[2] = z8; A0[3] = z8;                   \
    A1[0] = z8; A1[1] = z8; A1[2] = z8; A1[3] = z8;                   \
    if ((s0) >= 0) {                                                  \
      const u16* p = feats + (s0) * 64 + hi * 8;                      \
      A0[0] = *(const short8*)(p);                                    \
      A0[1] = *(const short8*)(p + 16);                               \
      A0[2] = *(const short8*)(p + 32);                               \
      A0[3] = *(const short8*)(p + 48);                               \
    }                                                                 \
    if ((s1) >= 0) {                                                  \
      const u16* p = feats + (s1) * 64 + hi * 8;                      \
      A1[0] = *(const short8*)(p);                                    \
      A1[1] = *(const short8*)(p + 16);                               \
      A1[2] = *(const short8*)(p + 32);                               \
      A1[3] = *(const short8*)(p + 48);                               \
    }                                                                 \
  }

#define DOMFMA(KIDX, A0, A1)                                                    \
  {                                                                             \
    const u16* wk = wbase + ((KIDX) << 12);                                     \
    _Pragma("unroll")                                                           \
    for (int kk = 0; kk < 4; ++kk) {                                            \
      short8 b0 = *(const short8*)(wk + kk * 16);                               \
      short8 b1 = *(const short8*)(wk + 2048 + kk * 16);                        \
      acc00 = __builtin_amdgcn_mfma_f32_32x32x16_bf16(A0[kk], b0, acc00, 0, 0, 0);\
      acc01 = __builtin_amdgcn_mfma_f32_32x32x16_bf16(A0[kk], b1, acc01, 0, 0, 0);\
      acc10 = __builtin_amdgcn_mfma_f32_32x32x16_bf16(A1[kk], b0, acc10, 0, 0, 0);\
      acc11 = __builtin_amdgcn_mfma_f32_32x32x16_bf16(A1[kk], b1, acc11, 0, 0, 0);\
    }                                                                           \
  }

  // ---- prologue: srcs for tiles 0 and 1, gather A tile 0 ----
  int sC0 = v0 ? inv[row0] : -1;
  int sC1 = v1 ? inv[row1] : -1;
  short8 Ac0[4], Ac1[4], An0[4], An1[4];
  GATHER(Ac0, Ac1, sC0, sC1);
  int sN0 = v0 ? inv[NV + row0] : -1;  // srcs for tile 1
  int sN1 = v1 ? inv[NV + row1] : -1;

  for (int k = 0; k < KOFF; k += 2) {
    // -------- even step: consume Ac (tile k) --------
    if (k + 1 < KOFF) GATHER(An0, An1, sN0, sN1);   // A for tile k+1 (srcs loaded last step)
    if (k + 2 < KOFF) {
      const int* ik = inv + (k + 2) * NV;
      sN0 = v0 ? ik[row0] : -1;
      sN1 = v1 ? ik[row1] : -1;
    }
    DOMFMA(k, Ac0, Ac1);
    if (k + 1 >= KOFF) break;
    // -------- odd step: consume An (tile k+1) --------
    if (k + 2 < KOFF) GATHER(Ac0, Ac1, sN0, sN1);   // A for tile k+2
    if (k + 3 < KOFF) {
      const int* ik = inv + (k + 3) * NV;
      sN0 = v0 ? ik[row0] : -1;
      sN1 = v1 ? ik[row1] : -1;
    }
    DOMFMA(k + 1, An0, An1);
  }
#undef GATHER
#undef DOMFMA

  // fused channel stats: lane holds col lo (n=0) / 32+lo (n=1); rows split across hi
  float s0 = 0.f, q0 = 0.f, s1 = 0.f, q1 = 0.f;
#pragma unroll
  for (int r = 0; r < 16; ++r) {
    s0 += acc00[r] + acc10[r];
    q0 += acc00[r] * acc00[r] + acc10[r] * acc10[r];
    s1 += acc01[r] + acc11[r];
    q1 += acc01[r] * acc01[r] + acc11[r] * acc11[r];
  }
  s0 += __shfl_xor(s0, 32, 64); q0 += __shfl_xor(q0, 32, 64);
  s1 += __shfl_xor(s1, 32, 64); q1 += __shfl_xor(q1, 32, 64);
  if (lane < 32) {
    redS[wave][lo] = s0; redQ[wave][lo] = q0;
    redS[wave][32 + lo] = s1; redQ[wave][32 + lo] = q1;
  }

  // epilogue: write pre-BN fp32. D layout: col = lane&31, row = (r&3) + 8*(r>>2) + 4*hi
#pragma unroll
  for (int r = 0; r < 16; ++r) {
    int rl = (r & 3) + ((r >> 2) * 8) + hi * 4;
    int ra = rbase + rl;
    int rb = rbase + 32 + rl;
    if (ra < NV) { out[ra * 64 + lo] = acc00[r]; out[ra * 64 + 32 + lo] = acc01[r]; }
    if (rb < NV) { out[rb * 64 + lo] = acc10[r]; out[rb * 64 + 32 + lo] = acc11[r]; }
  }

  __syncthreads();
  if (t < 64) {
    float s = redS[0][t] + redS[1][t] + redS[2][t] + redS[3][t];
    float q = redQ[0][t] + redQ[1][t] + redQ[2][t] + redQ[3][t];
    atomicAdd(&stats[t], s);
    atomicAdd(&stats[64 + t], q);
  }
}

// ---------------- apply BN + ReLU in place (stats finalize fused per block) ----------------
__global__ void k_apply(float* __restrict__ out, const float* __restrict__ stats,
                        const float* __restrict__ gamma, const float* __restrict__ beta) {
  __shared__ float sc[64], sh[64];
  const int t = threadIdx.x;
  if (t < 64) {
    float inv_n = 1.0f / (float)NV;
    float mean = stats[t] * inv_n;
    float var = stats[64 + t] * inv_n - mean * mean;
    float scale = gamma[t] * rsqrtf(var + EPS_BN);
    sc[t] = scale;
    sh[t] = beta[t] - mean * scale;
  }
  __syncthreads();
  int i = blockIdx.x * 256 + t;   // one float4 per thread
  if (i >= NV * 64 / 4) return;
  int c0 = (i & 15) * 4;
  float4 v = ((const float4*)out)[i];
  float* pv = (float*)&v;
#pragma unroll
  for (int j = 0; j < 4; ++j) {
    float y = pv[j] * sc[c0 + j] + sh[c0 + j];
    pv[j] = y > 0.f ? y : 0.f;
  }
  ((float4*)out)[i] = v;
}

extern "C" void kernel_launch(void* const* d_in, const int* in_sizes, int n_in,
                              void* d_out, int out_size, void* d_ws, size_t ws_size,
                              hipStream_t stream) {
  const float* feats = (const float*)d_in[0];
  const float* W     = (const float*)d_in[1];
  const float* gamma = (const float*)d_in[2];
  const float* beta  = (const float*)d_in[3];
  const float* mask  = (const float*)d_in[4];
  const int* in_idx  = (const int*)d_in[5];
  const int* out_idx = (const int*)d_in[6];
  float* out = (float*)d_out;

  char* ws = (char*)d_ws;
  int* inv = (int*)ws;                        // 43.2 MB
  u16* featsBf = (u16*)(ws + FEATSBF_OFF);    // 51.2 MB
  u16* Wt = (u16*)(ws + WT_OFF);              // 216 KB
  float* stats = (float*)(ws + STATS_OFF);    // 128 floats used

  hipMemsetAsync(inv, 0xFF, INV_BYTES, stream);              // inv = -1
  hipMemsetAsync(stats, 0, 128 * sizeof(float), stream);     // sum/sq = 0
  k_prep<<<PREP_BLOCKS, 256, 0, stream>>>(feats, featsBf, in_idx, out_idx, mask, inv, W, Wt);
  k_main<<<(NV + 255) / 256, 256, 0, stream>>>(featsBf, inv, Wt, out, stats);
  k_apply<<<NV * 64 / 4 / 256, 256, 0, stream>>>(out, stats, gamma, beta);
}

// Round 8
// 417.639 us; speedup vs baseline: 1.2737x; 1.2737x over previous
//
#include <hip/hip_runtime.h>
#include <stdint.h>

typedef unsigned short u16;
typedef unsigned int u32;

#define NV 400000
#define KOFF 27
#define EPS_BN 1e-5f

#define INV_ELEMS (KOFF * NV)            // 10.8M
#define INV_BYTES (INV_ELEMS * 4)        // 43.2 MB
#define FEATSBF_OFF INV_BYTES            // bf16 feats: 51.2 MB
#define WT_OFF (FEATSBF_OFF + NV * 64 * 2)
#define STATS_OFF (WT_OFF + KOFF * 64 * 64 * 2)

#define CVT_BLOCKS 25000                 // NV*64/4/256
#define BUILD_BLOCKS 42188               // ceil(INV_ELEMS/256)
#define WT_BLOCKS 432                    // ceil(KOFF*4096/256)
#define PREP_BLOCKS (CVT_BLOCKS + BUILD_BLOCKS + WT_BLOCKS)

using short8 = __attribute__((ext_vector_type(8))) short;
using floatx16 = __attribute__((ext_vector_type(16))) float;

__device__ __forceinline__ u16 f2bf(float f) {
  u32 u = __float_as_uint(f);
  u += 0x7FFFu + ((u >> 16) & 1u);
  return (u16)(u >> 16);
}

// ---------------- fused prep: cvt feats -> bf16 | build inv map | transpose W ----------------
__global__ void k_prep(const float* __restrict__ feats, u16* __restrict__ featsBf,
                       const int* __restrict__ in_idx, const int* __restrict__ out_idx,
                       const float* __restrict__ mask, int* __restrict__ inv,
                       const float* __restrict__ W, u16* __restrict__ Wt) {
  const int b = blockIdx.x;
  const int tid = threadIdx.x;
  if (b < CVT_BLOCKS) {
    // feats fp32 -> bf16, one float4 per thread
    int i = b * 256 + tid;
    float4 v = ((const float4*)feats)[i];
    ushort4 o;
    o.x = f2bf(v.x); o.y = f2bf(v.y); o.z = f2bf(v.z); o.w = f2bf(v.w);
    ((ushort4*)featsBf)[i] = o;
  } else if (b < CVT_BLOCKS + BUILD_BLOCKS) {
    // inverse map: inv[k][out_idx] = in_idx (valid out_idx distinct within k)
    int t = (b - CVT_BLOCKS) * 256 + tid;
    if (t < INV_ELEMS && mask[t] != 0.0f) {
      int k = t / NV;
      inv[k * NV + out_idx[t]] = in_idx[t];
    }
  } else {
    // Wt[k][o][c] = bf16(W[k][c][o])
    int t = (b - CVT_BLOCKS - BUILD_BLOCKS) * 256 + tid;
    if (t < KOFF * 64 * 64) {
      int k = t >> 12, rem = t & 4095, c = rem >> 6, o = rem & 63;
      Wt[(k << 12) + (o << 6) + c] = f2bf(W[t]);
    }
  }
}

// ---------------- main: phase-staged W (8 k-tiles per barrier pair) ----------------
// Block = 256 output rows, 4 waves, each wave owns a 64x64 tile (2x2 of 32x32).
// Wsm holds 8 k-tiles staged per phase: 27 k-steps need only 8 barriers total
// (vs 54), so the A-gather prefetch crosses no barrier in 7 of 8 steps and its
// latency truly hides under the 512-cycle MFMA shadow (syncthreads drains vmcnt,
// which nullified the per-k-barrier pipeline of earlier rounds).
// 70KB LDS + ~152 regs -> 2 blocks/CU co-resident to cover phase-boundary stalls.
__global__ void __launch_bounds__(256)
k_main(const u16* __restrict__ feats, const int* __restrict__ inv,
       const u16* __restrict__ Wt, float* __restrict__ out, float* __restrict__ stats) {
  __shared__ u16 Wsm[8][64][68];   // pitch 68: B-frag reads 2-way bank alias (free)
  __shared__ float redS[4][64];
  __shared__ float redQ[4][64];

  const int t = threadIdx.x;
  const int lane = t & 63;
  const int wave = t >> 6;
  const int lo = lane & 31;        // A row within 32-row group / D col within 32-col group
  const int hi = lane >> 5;        // k-half selector of the fragment
  const int rbase = blockIdx.x * 256 + wave * 64;
  const int row0 = rbase + lo;
  const int row1 = rbase + 32 + lo;
  const bool v0 = row0 < NV;
  const bool v1 = row1 < NV;

  const floatx16 z16 = {0.f, 0.f, 0.f, 0.f, 0.f, 0.f, 0.f, 0.f,
                        0.f, 0.f, 0.f, 0.f, 0.f, 0.f, 0.f, 0.f};
  floatx16 acc00 = z16, acc01 = z16, acc10 = z16, acc11 = z16;

  const int wr0 = t >> 3;          // staging: row within tile
  const int wc0 = (t & 7) * 8;     // staging: col (u16 units)

#define GATHER(A0, A1, s0, s1)                                        \
  {                                                                   \
    const short8 z8 = {0, 0, 0, 0, 0, 0, 0, 0};                       \
    A0[0] = z8; A0[1] = z8; A0[2] = z8; A0[3] = z8;                   \
    A1[0] = z8; A1[1] = z8; A1[2] = z8; A1[3] = z8;                   \
    if ((s0) >= 0) {                                                  \
      const u16* p = feats + (s0) * 64 + hi * 8;                      \
      A0[0] = *(const short8*)(p);                                    \
      A0[1] = *(const short8*)(p + 16);                               \
      A0[2] = *(const short8*)(p + 32);                               \
      A0[3] = *(const short8*)(p + 48);                               \
    }                                                                 \
    if ((s1) >= 0) {                                                  \
      const u16* p = feats + (s1) * 64 + hi * 8;                      \
      A1[0] = *(const short8*)(p);                                    \
      A1[1] = *(const short8*)(p + 16);                               \
      A1[2] = *(const short8*)(p + 32);                               \
      A1[3] = *(const short8*)(p + 48);                               \
    }                                                                 \
  }

#define DOMFMA(KT, A0, A1)                                                      \
  _Pragma("unroll")                                                             \
  for (int kk = 0; kk < 4; ++kk) {                                              \
    short8 b0 = *(const short8*)&Wsm[KT][lo][kk * 16 + hi * 8];                 \
    short8 b1 = *(const short8*)&Wsm[KT][32 + lo][kk * 16 + hi * 8];            \
    acc00 = __builtin_amdgcn_mfma_f32_32x32x16_bf16(A0[kk], b0, acc00, 0, 0, 0);\
    acc01 = __builtin_amdgcn_mfma_f32_32x32x16_bf16(A0[kk], b1, acc01, 0, 0, 0);\
    acc10 = __builtin_amdgcn_mfma_f32_32x32x16_bf16(A1[kk], b0, acc10, 0, 0, 0);\
    acc11 = __builtin_amdgcn_mfma_f32_32x32x16_bf16(A1[kk], b1, acc11, 0, 0, 0);\
  }

// stage PK tiles (PB..PB+PK-1) into Wsm[0..PK-1]; 2 x 16B per thread per tile
#define STAGE(PB, PK)                                                  \
  _Pragma("unroll")                                                    \
  for (int kt = 0; kt < (PK); ++kt) {                                  \
    const u16* wk = Wt + ((PB + kt) << 12);                            \
    uint4 wa = *(const uint4*)(wk + t * 8);                            \
    uint4 wb = *(const uint4*)(wk + (t + 256) * 8);                    \
    *(uint4*)&Wsm[kt][wr0][wc0] = wa;                                  \
    *(uint4*)&Wsm[kt][wr0 + 32][wc0] = wb;                             \
  }

// step consuming Ac, gathering next into An (even global k)
#define KSTEP_E(K, KT)                                                 \
  {                                                                    \
    if ((K) + 1 < KOFF) GATHER(An0, An1, sN0, sN1);                    \
    if ((K) + 2 < KOFF) {                                              \
      const int* ik = inv + ((K) + 2) * NV;                            \
      sN0 = v0 ? ik[row0] : -1;                                        \
      sN1 = v1 ? ik[row1] : -1;                                        \
    }                                                                  \
    DOMFMA(KT, Ac0, Ac1);                                              \
  }
// step consuming An, gathering next into Ac (odd global k)
#define KSTEP_O(K, KT)                                                 \
  {                                                                    \
    if ((K) + 1 < KOFF) GATHER(Ac0, Ac1, sN0, sN1);                    \
    if ((K) + 2 < KOFF) {                                              \
      const int* ik = inv + ((K) + 2) * NV;                            \
      sN0 = v0 ? ik[row0] : -1;                                        \
      sN1 = v1 ? ik[row1] : -1;                                        \
    }                                                                  \
    DOMFMA(KT, An0, An1);                                              \
  }

#define STEPS8(PB)                                                     \
  KSTEP_E(PB + 0, 0) KSTEP_O(PB + 1, 1) KSTEP_E(PB + 2, 2)             \
  KSTEP_O(PB + 3, 3) KSTEP_E(PB + 4, 4) KSTEP_O(PB + 5, 5)             \
  KSTEP_E(PB + 6, 6) KSTEP_O(PB + 7, 7)

  // ---- prologue: srcs for tiles 0/1, gather A tile 0 ----
  int sC0 = v0 ? inv[row0] : -1;
  int sC1 = v1 ? inv[row1] : -1;
  short8 Ac0[4], Ac1[4], An0[4], An1[4];
  GATHER(Ac0, Ac1, sC0, sC1);
  int sN0 = v0 ? inv[NV + row0] : -1;
  int sN1 = v1 ? inv[NV + row1] : -1;

  // ---- phase 0: k = 0..7 ----
  STAGE(0, 8);
  __syncthreads();
  STEPS8(0)
  // ---- phase 1: k = 8..15 ----
  __syncthreads();
  STAGE(8, 8);
  __syncthreads();
  STEPS8(8)
  // ---- phase 2: k = 16..23 ----
  __syncthreads();
  STAGE(16, 8);
  __syncthreads();
  STEPS8(16)
  // ---- phase 3: k = 24..26 ----
  __syncthreads();
  STAGE(24, 3);
  __syncthreads();
  KSTEP_E(24, 0) KSTEP_O(25, 1) KSTEP_E(26, 2)

#undef GATHER
#undef DOMFMA
#undef STAGE
#undef KSTEP_E
#undef KSTEP_O
#undef STEPS8

  // fused channel stats: lane holds col lo (n=0) / 32+lo (n=1); rows split across hi
  float s0 = 0.f, q0 = 0.f, s1 = 0.f, q1 = 0.f;
#pragma unroll
  for (int r = 0; r < 16; ++r) {
    s0 += acc00[r] + acc10[r];
    q0 += acc00[r] * acc00[r] + acc10[r] * acc10[r];
    s1 += acc01[r] + acc11[r];
    q1 += acc01[r] * acc01[r] + acc11[r] * acc11[r];
  }
  s0 += __shfl_xor(s0, 32, 64); q0 += __shfl_xor(q0, 32, 64);
  s1 += __shfl_xor(s1, 32, 64); q1 += __shfl_xor(q1, 32, 64);
  if (lane < 32) {
    redS[wave][lo] = s0; redQ[wave][lo] = q0;
    redS[wave][32 + lo] = s1; redQ[wave][32 + lo] = q1;
  }

  // epilogue: write pre-BN fp32. D layout: col = lane&31, row = (r&3) + 8*(r>>2) + 4*hi
#pragma unroll
  for (int r = 0; r < 16; ++r) {
    int rl = (r & 3) + ((r >> 2) * 8) + hi * 4;
    int ra = rbase + rl;
    int rb = rbase + 32 + rl;
    if (ra < NV) { out[ra * 64 + lo] = acc00[r]; out[ra * 64 + 32 + lo] = acc01[r]; }
    if (rb < NV) { out[rb * 64 + lo] = acc10[r]; out[rb * 64 + 32 + lo] = acc11[r]; }
  }

  __syncthreads();
  if (t < 64) {
    float s = redS[0][t] + redS[1][t] + redS[2][t] + redS[3][t];
    float q = redQ[0][t] + redQ[1][t] + redQ[2][t] + redQ[3][t];
    atomicAdd(&stats[t], s);
    atomicAdd(&stats[64 + t], q);
  }
}

// ---------------- apply BN + ReLU in place (stats finalize fused per block) ----------------
__global__ void k_apply(float* __restrict__ out, const float* __restrict__ stats,
                        const float* __restrict__ gamma, const float* __restrict__ beta) {
  __shared__ float sc[64], sh[64];
  const int t = threadIdx.x;
  if (t < 64) {
    float inv_n = 1.0f / (float)NV;
    float mean = stats[t] * inv_n;
    float var = stats[64 + t] * inv_n - mean * mean;
    float scale = gamma[t] * rsqrtf(var + EPS_BN);
    sc[t] = scale;
    sh[t] = beta[t] - mean * scale;
  }
  __syncthreads();
  int i = blockIdx.x * 256 + t;   // one float4 per thread
  if (i >= NV * 64 / 4) return;
  int c0 = (i & 15) * 4;
  float4 v = ((const float4*)out)[i];
  float* pv = (float*)&v;
#pragma unroll
  for (int j = 0; j < 4; ++j) {
    float y = pv[j] * sc[c0 + j] + sh[c0 + j];
    pv[j] = y > 0.f ? y : 0.f;
  }
  ((float4*)out)[i] = v;
}

extern "C" void kernel_launch(void* const* d_in, const int* in_sizes, int n_in,
                              void* d_out, int out_size, void* d_ws, size_t ws_size,
                              hipStream_t stream) {
  const float* feats = (const float*)d_in[0];
  const float* W     = (const float*)d_in[1];
  const float* gamma = (const float*)d_in[2];
  const float* beta  = (const float*)d_in[3];
  const float* mask  = (const float*)d_in[4];
  const int* in_idx  = (const int*)d_in[5];
  const int* out_idx = (const int*)d_in[6];
  float* out = (float*)d_out;

  char* ws = (char*)d_ws;
  int* inv = (int*)ws;                        // 43.2 MB
  u16* featsBf = (u16*)(ws + FEATSBF_OFF);    // 51.2 MB
  u16* Wt = (u16*)(ws + WT_OFF);              // 216 KB
  float* stats = (float*)(ws + STATS_OFF);    // 128 floats used

  hipMemsetAsync(inv, 0xFF, INV_BYTES, stream);              // inv = -1
  hipMemsetAsync(stats, 0, 128 * sizeof(float), stream);     // sum/sq = 0
  k_prep<<<PREP_BLOCKS, 256, 0, stream>>>(feats, featsBf, in_idx, out_idx, mask, inv, W, Wt);
  k_main<<<(NV + 255) / 256, 256, 0, stream>>>(featsBf, inv, Wt, out, stats);
  k_apply<<<NV * 64 / 4 / 256, 256, 0, stream>>>(out, stats, gamma, beta);
}

// Round 9
// 403.516 us; speedup vs baseline: 1.3183x; 1.0350x over previous
//
#include <hip/hip_runtime.h>
#include <stdint.h>

typedef unsigned short u16;
typedef unsigned int u32;

#define NV 400000
#define KOFF 27
#define EPS_BN 1e-5f

#define INV_ELEMS (KOFF * NV)            // 10.8M
#define INV_BYTES (INV_ELEMS * 4)        // 43.2 MB
#define FEATSBF_OFF INV_BYTES            // bf16 feats: 51.2 MB
#define WT_OFF (FEATSBF_OFF + NV * 64 * 2)
#define STATS_OFF (WT_OFF + KOFF * 64 * 64 * 2)

#define CVT_BLOCKS 25000                 // NV*64/4/256
#define BUILD_BLOCKS 42188               // ceil(INV_ELEMS/256)
#define WT_BLOCKS 432                    // ceil(KOFF*4096/256)
#define PREP_BLOCKS (CVT_BLOCKS + BUILD_BLOCKS + WT_BLOCKS)

#define MAIN_BLOCKS 3125                 // NV / 128 rows per block (exact)

using short8 = __attribute__((ext_vector_type(8))) short;
using floatx16 = __attribute__((ext_vector_type(16))) float;

__device__ __forceinline__ u16 f2bf(float f) {
  u32 u = __float_as_uint(f);
  u += 0x7FFFu + ((u >> 16) & 1u);
  return (u16)(u >> 16);
}

// ---------------- fused prep: cvt feats -> bf16 | build inv map | transpose W ----------------
__global__ void k_prep(const float* __restrict__ feats, u16* __restrict__ featsBf,
                       const int* __restrict__ in_idx, const int* __restrict__ out_idx,
                       const float* __restrict__ mask, int* __restrict__ inv,
                       const float* __restrict__ W, u16* __restrict__ Wt) {
  const int b = blockIdx.x;
  const int tid = threadIdx.x;
  if (b < CVT_BLOCKS) {
    // feats fp32 -> bf16, one float4 per thread
    int i = b * 256 + tid;
    float4 v = ((const float4*)feats)[i];
    ushort4 o;
    o.x = f2bf(v.x); o.y = f2bf(v.y); o.z = f2bf(v.z); o.w = f2bf(v.w);
    ((ushort4*)featsBf)[i] = o;
  } else if (b < CVT_BLOCKS + BUILD_BLOCKS) {
    // inverse map: inv[k][out_idx] = in_idx (valid out_idx distinct within k)
    int t = (b - CVT_BLOCKS) * 256 + tid;
    if (t < INV_ELEMS && mask[t] != 0.0f) {
      int k = t / NV;
      inv[k * NV + out_idx[t]] = in_idx[t];
    }
  } else {
    // Wt[k][o][c] = bf16(W[k][c][o])
    int t = (b - CVT_BLOCKS - BUILD_BLOCKS) * 256 + tid;
    if (t < KOFF * 64 * 64) {
      int k = t >> 12, rem = t & 4095, c = rem >> 6, o = rem & 63;
      Wt[(k << 12) + (o << 6) + c] = f2bf(W[t]);
    }
  }
}

// ---------------- main: 32x64 wave tile for 4 waves/SIMD occupancy ----------------
// Unified-RF arithmetic (gfx950: AGPR shares the VGPR budget; waves/SIMD halve at
// 64/128/256 regs): the 64x64-wave version was 88 VGPR + 64 AGPR = 152 -> 2 waves/SIMD,
// measured occupancy 17.8% = latency-bound. 32x64 tile: 32 AGPR acc + 32 VGPR A-frags
// + ~40 misc = ~105-115 unified -> 4 waves/SIMD (2x TLP). Block = 4 waves = 128 rows,
// grid = NV/128 = 3125 exactly (no row guards). K-loop is the proven round-5
// double-buffered-W structure (127.5us at 64x64): reg-prefetched W -> LDS (72-pitch,
// 0 bank conflicts), A gathered straight to MFMA fragment regs 1 tile ahead,
// inv srcs 2 tiles ahead.
__global__ void __launch_bounds__(256, 4)
k_main(const u16* __restrict__ feats, const int* __restrict__ inv,
       const u16* __restrict__ Wt, float* __restrict__ out, float* __restrict__ stats) {
  __shared__ u16 Wsm[2][64][72];   // 72-pitch: conflict-free frag reads (measured 0)
  __shared__ float redS[4][64];
  __shared__ float redQ[4][64];

  const int t = threadIdx.x;
  const int lane = t & 63;
  const int wave = t >> 6;
  const int lo = lane & 31;        // A row within the 32-row tile / D col within 32-col group
  const int hi = lane >> 5;        // k-half selector of the fragment
  const int rbase = blockIdx.x * 128 + wave * 32;
  const int row = rbase + lo;      // always < NV: 3125 * 128 == NV

  const floatx16 z16 = {0.f, 0.f, 0.f, 0.f, 0.f, 0.f, 0.f, 0.f,
                        0.f, 0.f, 0.f, 0.f, 0.f, 0.f, 0.f, 0.f};
  floatx16 acc0 = z16, acc1 = z16;   // cols 0-31 / 32-63

  const int wr0 = t >> 3;          // staging: row within tile
  const int wc0 = (t & 7) * 8;     // staging: col (u16 units)

#define GATHER(A, s)                                                  \
  {                                                                   \
    const short8 z8 = {0, 0, 0, 0, 0, 0, 0, 0};                       \
    A[0] = z8; A[1] = z8; A[2] = z8; A[3] = z8;                       \
    if ((s) >= 0) {                                                   \
      const u16* p = feats + (s) * 64 + hi * 8;                       \
      A[0] = *(const short8*)(p);                                     \
      A[1] = *(const short8*)(p + 16);                                \
      A[2] = *(const short8*)(p + 32);                                \
      A[3] = *(const short8*)(p + 48);                                \
    }                                                                 \
  }

#define DOMFMA(BUF, A)                                                          \
  _Pragma("unroll")                                                             \
  for (int kk = 0; kk < 4; ++kk) {                                              \
    short8 b0 = *(const short8*)&Wsm[BUF][lo][kk * 16 + hi * 8];                \
    short8 b1 = *(const short8*)&Wsm[BUF][32 + lo][kk * 16 + hi * 8];           \
    acc0 = __builtin_amdgcn_mfma_f32_32x32x16_bf16(A[kk], b0, acc0, 0, 0, 0);   \
    acc1 = __builtin_amdgcn_mfma_f32_32x32x16_bf16(A[kk], b1, acc1, 0, 0, 0);   \
  }

  // ---- prologue: W tile 0 in regs, srcs for tiles 0/1, gather A tile 0 ----
  uint4 wEa = *(const uint4*)(Wt + t * 8);
  uint4 wEb = *(const uint4*)(Wt + (t + 256) * 8);
  uint4 wOa = wEa, wOb = wEb;
  int sC = inv[row];
  short8 Ac[4], An[4];
  GATHER(Ac, sC);
  int sO = inv[NV + row];          // src for tile 1
  int sE = -1;

  for (int k = 0; k < KOFF; k += 2) {
    // -------- even step: tile k in buf 0 --------
    *(uint4*)&Wsm[0][wr0][wc0] = wEa;
    *(uint4*)&Wsm[0][wr0 + 32][wc0] = wEb;
    if (k + 1 < KOFF) {
      const u16* wk = Wt + ((k + 1) << 12);
      wOa = *(const uint4*)(wk + t * 8);
      wOb = *(const uint4*)(wk + (t + 256) * 8);
    }
    if (k + 2 < KOFF) sE = inv[(k + 2) * NV + row];
    if (k + 1 < KOFF) GATHER(An, sO);   // A for tile k+1
    __syncthreads();
    DOMFMA(0, Ac);
    if (k + 1 >= KOFF) break;
    // -------- odd step: tile k+1 in buf 1 --------
    *(uint4*)&Wsm[1][wr0][wc0] = wOa;
    *(uint4*)&Wsm[1][wr0 + 32][wc0] = wOb;
    if (k + 2 < KOFF) {
      const u16* wk = Wt + ((k + 2) << 12);
      wEa = *(const uint4*)(wk + t * 8);
      wEb = *(const uint4*)(wk + (t + 256) * 8);
    }
    if (k + 3 < KOFF) sO = inv[(k + 3) * NV + row];
    if (k + 2 < KOFF) GATHER(Ac, sE);   // A for tile k+2
    __syncthreads();
    DOMFMA(1, An);
  }
#undef GATHER
#undef DOMFMA

  // fused channel stats: lane holds col lo (acc0) / 32+lo (acc1); rows split across hi
  float s0 = 0.f, q0 = 0.f, s1 = 0.f, q1 = 0.f;
#pragma unroll
  for (int r = 0; r < 16; ++r) {
    s0 += acc0[r];
    q0 += acc0[r] * acc0[r];
    s1 += acc1[r];
    q1 += acc1[r] * acc1[r];
  }
  s0 += __shfl_xor(s0, 32, 64); q0 += __shfl_xor(q0, 32, 64);
  s1 += __shfl_xor(s1, 32, 64); q1 += __shfl_xor(q1, 32, 64);
  if (lane < 32) {
    redS[wave][lo] = s0; redQ[wave][lo] = q0;
    redS[wave][32 + lo] = s1; redQ[wave][32 + lo] = q1;
  }

  // epilogue: write pre-BN fp32. D layout: col = lane&31, row = (r&3) + 8*(r>>2) + 4*hi
#pragma unroll
  for (int r = 0; r < 16; ++r) {
    int rl = (r & 3) + ((r >> 2) * 8) + hi * 4;
    int ra = rbase + rl;
    out[ra * 64 + lo] = acc0[r];
    out[ra * 64 + 32 + lo] = acc1[r];
  }

  __syncthreads();
  if (t < 64) {
    float s = redS[0][t] + redS[1][t] + redS[2][t] + redS[3][t];
    float q = redQ[0][t] + redQ[1][t] + redQ[2][t] + redQ[3][t];
    atomicAdd(&stats[t], s);
    atomicAdd(&stats[64 + t], q);
  }
}

// ---------------- apply BN + ReLU in place (stats finalize fused per block) ----------------
__global__ void k_apply(float* __restrict__ out, const float* __restrict__ stats,
                        const float* __restrict__ gamma, const float* __restrict__ beta) {
  __shared__ float sc[64], sh[64];
  const int t = threadIdx.x;
  if (t < 64) {
    float inv_n = 1.0f / (float)NV;
    float mean = stats[t] * inv_n;
    float var = stats[64 + t] * inv_n - mean * mean;
    float scale = gamma[t] * rsqrtf(var + EPS_BN);
    sc[t] = scale;
    sh[t] = beta[t] - mean * scale;
  }
  __syncthreads();
  int i = blockIdx.x * 256 + t;   // one float4 per thread
  if (i >= NV * 64 / 4) return;
  int c0 = (i & 15) * 4;
  float4 v = ((const float4*)out)[i];
  float* pv = (float*)&v;
#pragma unroll
  for (int j = 0; j < 4; ++j) {
    float y = pv[j] * sc[c0 + j] + sh[c0 + j];
    pv[j] = y > 0.f ? y : 0.f;
  }
  ((float4*)out)[i] = v;
}

extern "C" void kernel_launch(void* const* d_in, const int* in_sizes, int n_in,
                              void* d_out, int out_size, void* d_ws, size_t ws_size,
                              hipStream_t stream) {
  const float* feats = (const float*)d_in[0];
  const float* W     = (const float*)d_in[1];
  const float* gamma = (const float*)d_in[2];
  const float* beta  = (const float*)d_in[3];
  const float* mask  = (const float*)d_in[4];
  const int* in_idx  = (const int*)d_in[5];
  const int* out_idx = (const int*)d_in[6];
  float* out = (float*)d_out;

  char* ws = (char*)d_ws;
  int* inv = (int*)ws;                        // 43.2 MB
  u16* featsBf = (u16*)(ws + FEATSBF_OFF);    // 51.2 MB
  u16* Wt = (u16*)(ws + WT_OFF);              // 216 KB
  float* stats = (float*)(ws + STATS_OFF);    // 128 floats used

  hipMemsetAsync(inv, 0xFF, INV_BYTES, stream);              // inv = -1
  hipMemsetAsync(stats, 0, 128 * sizeof(float), stream);     // sum/sq = 0
  k_prep<<<PREP_BLOCKS, 256, 0, stream>>>(feats, featsBf, in_idx, out_idx, mask, inv, W, Wt);
  k_main<<<MAIN_BLOCKS, 256, 0, stream>>>(featsBf, inv, Wt, out, stats);
  k_apply<<<NV * 64 / 4 / 256, 256, 0, stream>>>(out, stats, gamma, beta);
}